// Round 15
// baseline (86.396 us; speedup 1.0000x reference)
//
#include <hip/hip_runtime.h>
#include <hip/hip_bf16.h>

#define N_IMG 2
#define HW 65536
#define PRE 1024
#define POST 256
#define NBIN 4096
#define SORTN 4096
#define NMS_THR 0.7f
#define SCORE_T 0.1f
#define MIN_SZ 4.0f
#define TRIPAIRS 523776          // 1024*1023/2 per image
#define TRITOTAL (2 * TRIPAIRS)  // 1047552

// ---------- helpers ----------
__device__ __forceinline__ unsigned int fkey(float f) {
    unsigned int u = __float_as_uint(f);
    return u ^ ((u & 0x80000000u) ? 0xFFFFFFFFu : 0x80000000u);
}
__device__ __forceinline__ float unfkey(unsigned int k) {
    unsigned int u = (k & 0x80000000u) ? (k ^ 0x80000000u) : ~k;
    return __uint_as_float(u);
}
__device__ __forceinline__ unsigned long long readlane64(unsigned long long v, int l) {
    unsigned int lo = (unsigned int)__builtin_amdgcn_readlane((int)(unsigned int)v, l);
    unsigned int hi = (unsigned int)__builtin_amdgcn_readlane((int)(unsigned int)(v >> 32), l);
    return ((unsigned long long)hi << 32) | (unsigned long long)lo;
}

// ============================================================================
// K1 (fused init+hist): zero masks/cnts; 2-way replicated LDS histogram
// (halves hot-bin atomic serialization) -> PRIVATE partial-hist region.
// 16 blocks x 1024: blockIdx = img*8 + seg.
// ============================================================================
__global__ __launch_bounds__(1024) void k_front(const float* __restrict__ obj,
                                                unsigned int* phist,
                                                unsigned long long* masks,
                                                unsigned int* cnts) {
    __shared__ unsigned int lh[2][NBIN];                  // 32 KB
    int img = blockIdx.x >> 3;
    int seg = blockIdx.x & 7;
    int cp = (threadIdx.x >> 9) & 1;                      // copy per half-block
    for (int i = threadIdx.x; i < NBIN; i += 1024) { lh[0][i] = 0u; lh[1][i] = 0u; }
    {
        unsigned long long* mz = masks + (size_t)blockIdx.x * 2048;
        mz[threadIdx.x] = 0ULL;
        mz[threadIdx.x + 1024] = 0ULL;
    }
    if (blockIdx.x == 0 && threadIdx.x < 8) cnts[threadIdx.x] = 0u;
    __syncthreads();
    const float4* o4 = (const float4*)(obj + (size_t)img * HW);
    int base = seg * 2048;
#pragma unroll
    for (int k = 0; k < 2; ++k) {
        float4 v = o4[base + threadIdx.x + k * 1024];
        atomicAdd(&lh[cp][fkey(v.x) >> 20], 1u);
        atomicAdd(&lh[cp][fkey(v.y) >> 20], 1u);
        atomicAdd(&lh[cp][fkey(v.z) >> 20], 1u);
        atomicAdd(&lh[cp][fkey(v.w) >> 20], 1u);
    }
    __syncthreads();
    unsigned int* ph = phist + (size_t)blockIdx.x * NBIN;
    for (int i = threadIdx.x; i < NBIN; i += 1024) ph[i] = lh[0][i] + lh[1][i];
}

// ============================================================================
// K2 (fused findbin+compact): each of 64 blocks redundantly computes selB for
// both images from the partial hists (proven scan), then compacts candidates
// with block-LDS aggregation and one global atomic per block per image.
// ============================================================================
__global__ __launch_bounds__(256) void k_compact(const float* __restrict__ obj,
                                                 const unsigned int* __restrict__ phist,
                                                 unsigned int* cnts, unsigned long long* cbuf) {
    __shared__ unsigned int lh[NBIN];                     // 16 KB
    __shared__ unsigned int chunk[256];
    __shared__ unsigned int sB[2];
    __shared__ unsigned long long lbuf[1024];             // 8 KB
    __shared__ unsigned int lcnt, lbase;
    int tid = threadIdx.x;

    // --- fused findbin: selB for both images (redundant per block, parallel)
    for (int img = 0; img < N_IMG; ++img) {
        for (int c = 0; c < 16; ++c) {                    // coalesced: bin = c*256+tid
            int b = c * 256 + tid;
            unsigned int v = 0;
#pragma unroll
            for (int q = 0; q < 8; ++q) v += phist[(size_t)(img * 8 + q) * NBIN + b];
            lh[b] = v;
        }
        __syncthreads();
        unsigned int s = 0;
        for (int k = 0; k < 16; ++k) s += lh[tid * 16 + k];
        chunk[tid] = s;
        __syncthreads();
        if (tid == 0) {
            unsigned int run = 0;
            int c;
            for (c = 255; c >= 0; --c) {
                if (run + chunk[c] >= PRE) break;
                run += chunk[c];
            }
            unsigned int B = 0;
            for (int b = c * 16 + 15; b >= c * 16; --b) {
                if (run + lh[b] >= PRE) { B = (unsigned int)b; break; }
                run += lh[b];
            }
            sB[img] = B;
        }
        __syncthreads();                                  // protect lh reuse
    }

    // --- compact
    int t = blockIdx.x * 256 + tid;
    const float4* o4 = (const float4*)obj;
#pragma unroll
    for (int k = 0; k < N_IMG; ++k) {
        if (tid == 0) lcnt = 0;
        __syncthreads();
        int p = t + k * 16384;                            // img = k (uniform)
        int img = p >> 14;
        unsigned int B = sB[img];
        float4 v = o4[p];
        float vs[4] = {v.x, v.y, v.z, v.w};
#pragma unroll
        for (int c = 0; c < 4; ++c) {
            unsigned int key = fkey(vs[c]);
            if ((key >> 20) >= B) {
                unsigned int i = (unsigned int)((p & 16383) * 4 + c);
                unsigned int pos = atomicAdd(&lcnt, 1u);
                lbuf[pos] = ((unsigned long long)key << 32) |
                            (unsigned long long)(0xFFFFFFFFu - i);
            }
        }
        __syncthreads();
        if (tid == 0) lbase = atomicAdd(&cnts[img], lcnt);
        __syncthreads();
        unsigned int n = lcnt, base = lbase;
        for (unsigned int q = tid; q < n; q += 256) {
            unsigned int gp = base + q;
            if (gp < SORTN) cbuf[img * SORTN + gp] = lbuf[q];
        }
        __syncthreads();
    }
}

// ============================================================================
// K3 (fused rank+decode)
// ============================================================================
__device__ __forceinline__ void decode_one(unsigned long long cv, int img,
                                           const float* __restrict__ boxreg,
                                           float* boxes, float* corn, float4* circ,
                                           unsigned int* varr, float* tscr, int r) {
    int g = img * PRE + r;
    unsigned int key = (unsigned int)(cv >> 32);
    unsigned int idx = (0xFFFFFFFFu - (unsigned int)(cv & 0xFFFFFFFFULL)) & 0xFFFFu;
    float sc = unfkey(key);
    int h = (int)(idx >> 8);
    int w = (int)(idx & 255u);
    const float* rg = boxreg + (size_t)img * 5 * HW;
    float t_ = rg[0 * HW + idx] * 1024.0f;
    float rr = rg[1 * HW + idx] * 1024.0f;
    float bb = rg[2 * HW + idx] * 1024.0f;
    float ll = rg[3 * HW + idx] * 1024.0f;
    float ang = (rg[4 * HW + idx] - 0.5f) * 90.0f;
    float wd = ll + rr;
    float ht = t_ + bb;
    float xc = (float)w * 4.0f + 0.5f * (rr - ll);
    float yc = (float)h * 4.0f + 0.5f * (bb - t_);
    xc = fminf(fmaxf(xc, 0.0f), 1023.0f);
    yc = fminf(fmaxf(yc, 0.0f), 1023.0f);
    bool valid = (sc > SCORE_T) && (wd >= MIN_SZ) && (ht >= MIN_SZ);

    float* bx = boxes + (size_t)g * 5;
    bx[0] = xc; bx[1] = yc; bx[2] = wd; bx[3] = ht; bx[4] = ang;
    tscr[g] = sc;
    varr[g] = valid ? 1u : 0u;

    float th = ang * (float)(3.14159265358979323846 / 180.0);
    float c = cosf(th), s = sinf(th);
    const float dxs[4] = {-0.5f, 0.5f, 0.5f, -0.5f};
    const float dys[4] = {-0.5f, -0.5f, 0.5f, 0.5f};
    float* cr = corn + (size_t)g * 8;
#pragma unroll
    for (int k = 0; k < 4; ++k) {
        float dx = dxs[k] * wd, dy = dys[k] * ht;
        cr[2 * k]     = xc + dx * c - dy * s;
        cr[2 * k + 1] = yc + dx * s + dy * c;
    }
    circ[g] = make_float4(xc, yc, 0.5f * sqrtf(wd * wd + ht * ht) + 0.01f, wd * ht);
}

__global__ __launch_bounds__(256) void k_rankdec(const unsigned int* __restrict__ cnts,
                                                 const unsigned long long* __restrict__ cbuf,
                                                 const float* __restrict__ boxreg,
                                                 float* boxes, float* corn, float4* circ,
                                                 unsigned int* varr, float* tscr) {
    __shared__ unsigned long long keys[SORTN];
    int img = blockIdx.x >> 4;
    int slice = blockIdx.x & 15;
    unsigned int M = cnts[img]; if (M > SORTN) M = SORTN;
    for (unsigned int i = threadIdx.x; i < M; i += 256) keys[i] = cbuf[img * SORTN + i];
    __syncthreads();
    unsigned int cid = (unsigned int)slice * 256 + threadIdx.x;
    if (cid >= M) return;
    unsigned long long cv = keys[cid];
    unsigned int r = 0;
    for (unsigned int j = 0; j < M; ++j) r += (keys[j] > cv) ? 1u : 0u;
    if (r < PRE) decode_one(cv, img, boxreg, boxes, corn, circ, varr, tscr, (int)r);
}

// ============================================================================
// K4 (fused pairs+clip), triangular enumeration (8 iters, exactly j>i pairs).
// ============================================================================
__global__ __launch_bounds__(256) void k_pairclip(const float4* __restrict__ circ,
                                                  const float* __restrict__ corn,
                                                  unsigned long long* masks) {
    __shared__ struct {
        float SPX[8][256], SPY[8][256], SQX[8][256], SQY[8][256];
        unsigned int plist[1280];
    } e;
    __shared__ unsigned int pcnt;
    int tid = threadIdx.x;
    if (tid == 0) pcnt = 0;
    __syncthreads();
    int t0 = blockIdx.x * 256 + tid;                      // 131072 threads
    for (int k = 0; k < 8; ++k) {
        int s = t0 + k * 131072;                          // 1048576 slots, 1047552 real
        if (s < TRITOTAL) {
            int img = (s >= TRIPAIRS) ? 1 : 0;
            int p = s - img * TRIPAIRS;
            int r = (int)((sqrtf((float)(8 * p + 1)) - 1.0f) * 0.5f);
            while ((r * (r + 1)) / 2 > p) --r;
            while (((r + 1) * (r + 2)) / 2 <= p) ++r;
            int i = p - (r * (r + 1)) / 2;
            int j = r + 1;
            float4 a = circ[img * PRE + i];
            float4 b = circ[img * PRE + j];
            float dx = b.x - a.x, dy = b.y - a.y, rr = a.z + b.z;
            if (dx * dx + dy * dy <= rr * rr)
                e.plist[atomicAdd(&pcnt, 1u)] =
                    ((unsigned int)img << 20) | ((unsigned int)i << 10) | (unsigned int)j;
        }
        __syncthreads();
        unsigned int n = pcnt;                            // uniform
        if (n >= 1024 || k == 7) {
            for (unsigned int q = tid; q < n; q += 256) {
                unsigned int pr = e.plist[q];
                int im = (int)(pr >> 20);
                int bi = (int)((pr >> 10) & 1023);
                int bj = (int)(pr & 1023);
                int ra = im * PRE + bi, rb = im * PRE + bj;
                const float4* ca = (const float4*)(corn + (size_t)ra * 8);
                float4 a0 = ca[0], a1 = ca[1];
                const float4* cb = (const float4*)(corn + (size_t)rb * 8);
                float4 b0 = cb[0], b1 = cb[1];
                float cbx[4] = {b0.x, b0.z, b1.x, b1.z};
                float cby[4] = {b0.y, b0.w, b1.y, b1.w};
                e.SPX[0][tid] = a0.x; e.SPY[0][tid] = a0.y;
                e.SPX[1][tid] = a0.z; e.SPY[1][tid] = a0.w;
                e.SPX[2][tid] = a1.x; e.SPY[2][tid] = a1.y;
                e.SPX[3][tid] = a1.z; e.SPY[3][tid] = a1.w;
                int n2 = 4;
#pragma unroll
                for (int ed = 0; ed < 4; ++ed) {
                    float (*PX)[256] = (ed & 1) ? e.SQX : e.SPX;
                    float (*PY)[256] = (ed & 1) ? e.SQY : e.SPY;
                    float (*QX)[256] = (ed & 1) ? e.SPX : e.SQX;
                    float (*QY)[256] = (ed & 1) ? e.SPY : e.SQY;
                    float p1x = cbx[ed], p1y = cby[ed];
                    int e2 = (ed + 1) & 3;
                    float ex = cbx[e2] - p1x, ey = cby[e2] - p1y;
                    int m = 0;
                    for (int kk = 0; kk < n2; ++kk) {
                        int kn = (kk + 1 < n2) ? kk + 1 : 0;
                        float cx_ = PX[kk][tid], cy_ = PY[kk][tid];
                        float nx_ = PX[kn][tid], ny_ = PY[kn][tid];
                        float dc = ex * (cy_ - p1y) - ey * (cx_ - p1x);
                        float dn = ex * (ny_ - p1y) - ey * (nx_ - p1x);
                        bool ic = dc >= 0.0f;
                        bool inx = dn >= 0.0f;
                        if (ic && m < 8) { QX[m][tid] = cx_; QY[m][tid] = cy_; ++m; }
                        if ((ic != inx) && m < 8) {
                            float den = dc - dn;
                            float safe = (fabsf(den) > 1e-9f) ? den : 1.0f;
                            float tt = dc / safe;
                            QX[m][tid] = cx_ + tt * (nx_ - cx_);
                            QY[m][tid] = cy_ + tt * (ny_ - cy_);
                            ++m;
                        }
                    }
                    n2 = m;
                }
                float inter = 0.0f;
                if (n2 >= 3) {
                    float sa = 0.0f;
                    for (int kk = 0; kk < n2; ++kk) {
                        int kn = (kk + 1 < n2) ? kk + 1 : 0;
                        sa += e.SPX[kk][tid] * e.SPY[kn][tid] - e.SPX[kn][tid] * e.SPY[kk][tid];
                    }
                    inter = 0.5f * fabsf(sa);
                }
                float uni = circ[ra].w + circ[rb].w - inter;
                float iou = inter / fmaxf(uni, 1e-9f);
                if (iou > NMS_THR)
                    atomicOr(&masks[(size_t)ra * 16 + (bj >> 6)], 1ULL << (bj & 63));
            }
            __syncthreads();
            if (tid == 0) pcnt = 0;
            __syncthreads();
        }
    }
}

// ============================================================================
// K5: greedy NMS + output. LDS-staged masks; skip-scan with batch-8
// speculative reads.
// ============================================================================
__global__ __launch_bounds__(1024) void k_nms_out(const unsigned long long* __restrict__ masks,
                                                  const unsigned int* __restrict__ varr,
                                                  const float* __restrict__ boxes,
                                                  const float* __restrict__ tscr,
                                                  float* __restrict__ out) {
    __shared__ unsigned long long lm[PRE * 16];   // 128 KB
    __shared__ unsigned long long vmw_s[16];
    __shared__ unsigned short keptIdx[POST];
    __shared__ int sTotal;
    int img = blockIdx.x;
    int t = threadIdx.x;
    const unsigned long long* mbase = masks + (size_t)img * PRE * 16;
    {
        const ulonglong2* src = (const ulonglong2*)mbase;
        ulonglong2* dst = (ulonglong2*)lm;
#pragma unroll
        for (int k = 0; k < 8; ++k) dst[t + k * 1024] = src[t + k * 1024];
    }
    {
        unsigned long long bal = __ballot(varr[img * PRE + t] != 0u);
        if ((t & 63) == 0) vmw_s[t >> 6] = bal;
    }
    __syncthreads();
    if (t < 64) {
        int lane = t;
        int lw = lane & 15;
        unsigned long long vmw = vmw_s[lw];
        unsigned long long supw = 0ULL;
        int cnt = 0;
        for (int b = 0; b < 16 && cnt < POST; ++b) {
            unsigned long long avail = readlane64(vmw, b) & ~readlane64(supw, b);
            while (avail && cnt < POST) {
                unsigned long long a = avail;
                int d0 = __ffsll((long long)a) - 1; a &= a - 1;
                int d1 = a ? __ffsll((long long)a) - 1 : 64; a &= a - 1;
                int d2 = a ? __ffsll((long long)a) - 1 : 64; a &= a - 1;
                int d3 = a ? __ffsll((long long)a) - 1 : 64; a &= a - 1;
                int d4 = a ? __ffsll((long long)a) - 1 : 64; a &= a - 1;
                int d5 = a ? __ffsll((long long)a) - 1 : 64; a &= a - 1;
                int d6 = a ? __ffsll((long long)a) - 1 : 64; a &= a - 1;
                int d7 = a ? __ffsll((long long)a) - 1 : 64; a &= a - 1;
                int r0 = b * 64 + d0;
                int r1 = b * 64 + (d1 & 63);
                int r2 = b * 64 + (d2 & 63);
                int r3 = b * 64 + (d3 & 63);
                int r4 = b * 64 + (d4 & 63);
                int r5 = b * 64 + (d5 & 63);
                int r6 = b * 64 + (d6 & 63);
                int r7 = b * 64 + (d7 & 63);
                unsigned long long w0 = lm[r0 * 16 + lw];
                unsigned long long w1 = lm[r1 * 16 + lw];
                unsigned long long w2 = lm[r2 * 16 + lw];
                unsigned long long w3 = lm[r3 * 16 + lw];
                unsigned long long w4 = lm[r4 * 16 + lw];
                unsigned long long w5 = lm[r5 * 16 + lw];
                unsigned long long w6 = lm[r6 * 16 + lw];
                unsigned long long w7 = lm[r7 * 16 + lw];
                unsigned long long sb = readlane64(w0, b);   // r0 always kept
                supw |= w0;
                if (lane == 0) keptIdx[cnt] = (unsigned short)r0;
                ++cnt;
                if (d1 < 64 && cnt < POST && !((sb >> d1) & 1ULL)) {
                    sb |= readlane64(w1, b); supw |= w1;
                    if (lane == 0) keptIdx[cnt] = (unsigned short)r1;
                    ++cnt;
                }
                if (d2 < 64 && cnt < POST && !((sb >> d2) & 1ULL)) {
                    sb |= readlane64(w2, b); supw |= w2;
                    if (lane == 0) keptIdx[cnt] = (unsigned short)r2;
                    ++cnt;
                }
                if (d3 < 64 && cnt < POST && !((sb >> d3) & 1ULL)) {
                    sb |= readlane64(w3, b); supw |= w3;
                    if (lane == 0) keptIdx[cnt] = (unsigned short)r3;
                    ++cnt;
                }
                if (d4 < 64 && cnt < POST && !((sb >> d4) & 1ULL)) {
                    sb |= readlane64(w4, b); supw |= w4;
                    if (lane == 0) keptIdx[cnt] = (unsigned short)r4;
                    ++cnt;
                }
                if (d5 < 64 && cnt < POST && !((sb >> d5) & 1ULL)) {
                    sb |= readlane64(w5, b); supw |= w5;
                    if (lane == 0) keptIdx[cnt] = (unsigned short)r5;
                    ++cnt;
                }
                if (d6 < 64 && cnt < POST && !((sb >> d6) & 1ULL)) {
                    sb |= readlane64(w6, b); supw |= w6;
                    if (lane == 0) keptIdx[cnt] = (unsigned short)r6;
                    ++cnt;
                }
                if (d7 < 64 && cnt < POST && !((sb >> d7) & 1ULL)) {
                    sb |= readlane64(w7, b); supw |= w7;
                    if (lane == 0) keptIdx[cnt] = (unsigned short)r7;
                    ++cnt;
                }
                avail = a & ~sb;
            }
        }
        if (lane == 0) sTotal = cnt;
    }
    __syncthreads();
    int total = sTotal;
    if (t < POST) {
        float v0 = 0.f, v1 = 0.f, v2 = 0.f, v3 = 0.f, v4 = 0.f, v5 = 0.f;
        if (t < total) {
            int i = keptIdx[t];
            const float* b = boxes + (size_t)(img * PRE + i) * 5;
            v0 = b[0]; v1 = b[1]; v2 = b[2]; v3 = b[3]; v4 = b[4];
            v5 = tscr[img * PRE + i];
        }
        float* o2 = out + (size_t)(img * POST + t) * 6;
        o2[0] = v0; o2[1] = v1; o2[2] = v2; o2[3] = v3; o2[4] = v4; o2[5] = v5;
    }
}

// ---------- workspace layout ----------
enum : size_t {
    OFF_BOX   = 0,         // 40960
    OFF_CORN  = 40960,     // 65536  -> 106496
    OFF_CIRC  = 106496,    // 32768  -> 139264
    OFF_VARR  = 139264,    // 8192   -> 147456
    OFF_TSCR  = 147456,    // 8192   -> 155648
    OFF_MASK  = 155648,    // 262144 -> 417792
    OFF_PHIST = 417792,    // 262144 -> 679936
    OFF_CNTS  = 679936,    // 32     -> 679968
    OFF_CBUF  = 679968,    // 65536  -> 745504
};

extern "C" void kernel_launch(void* const* d_in, const int* in_sizes, int n_in,
                              void* d_out, int out_size, void* d_ws, size_t ws_size,
                              hipStream_t stream) {
    const float* obj = (const float*)d_in[0];
    const float* boxreg = (const float*)d_in[1];
    float* out = (float*)d_out;

    char* w = (char*)d_ws;
    float* boxes = (float*)(w + OFF_BOX);
    float* corn = (float*)(w + OFF_CORN);
    float4* circ = (float4*)(w + OFF_CIRC);
    unsigned int* varr = (unsigned int*)(w + OFF_VARR);
    float* tscr = (float*)(w + OFF_TSCR);
    unsigned long long* masks = (unsigned long long*)(w + OFF_MASK);
    unsigned int* phist = (unsigned int*)(w + OFF_PHIST);
    unsigned int* cnts = (unsigned int*)(w + OFF_CNTS);
    unsigned long long* cbuf = (unsigned long long*)(w + OFF_CBUF);

    k_front<<<16, 1024, 0, stream>>>(obj, phist, masks, cnts);
    k_compact<<<64, 256, 0, stream>>>(obj, phist, cnts, cbuf);
    k_rankdec<<<32, 256, 0, stream>>>(cnts, cbuf, boxreg, boxes, corn, circ, varr, tscr);
    k_pairclip<<<512, 256, 0, stream>>>(circ, corn, masks);
    k_nms_out<<<N_IMG, 1024, 0, stream>>>(masks, varr, boxes, tscr, out);
}

// Round 16
// 83.310 us; speedup vs baseline: 1.0370x; 1.0370x over previous
//
#include <hip/hip_runtime.h>
#include <hip/hip_bf16.h>

#define N_IMG 2
#define HW 65536
#define PRE 1024
#define POST 256
#define NBIN 4096
#define SORTN 4096
#define NMS_THR 0.7f
#define SCORE_T 0.1f
#define MIN_SZ 4.0f
#define TRIPAIRS 523776          // 1024*1023/2 per image
#define TRITOTAL (2 * TRIPAIRS)  // 1047552

// ---------- helpers ----------
__device__ __forceinline__ unsigned int fkey(float f) {
    unsigned int u = __float_as_uint(f);
    return u ^ ((u & 0x80000000u) ? 0xFFFFFFFFu : 0x80000000u);
}
__device__ __forceinline__ float unfkey(unsigned int k) {
    unsigned int u = (k & 0x80000000u) ? (k ^ 0x80000000u) : ~k;
    return __uint_as_float(u);
}
__device__ __forceinline__ unsigned long long readlane64(unsigned long long v, int l) {
    unsigned int lo = (unsigned int)__builtin_amdgcn_readlane((int)(unsigned int)v, l);
    unsigned int hi = (unsigned int)__builtin_amdgcn_readlane((int)(unsigned int)(v >> 32), l);
    return ((unsigned long long)hi << 32) | (unsigned long long)lo;
}

// ============================================================================
// K1 (fused init+hist): zero masks/cnts; per-block LDS histogram -> PRIVATE
// partial-hist region (plain stores; no global atomics, no pre-zeroed hist).
// ============================================================================
__global__ __launch_bounds__(1024) void k_front(const float* __restrict__ obj,
                                                unsigned int* phist,
                                                unsigned long long* masks,
                                                unsigned int* cnts) {
    __shared__ unsigned int lh[NBIN];
    int img = blockIdx.x >> 3;
    int seg = blockIdx.x & 7;
    for (int i = threadIdx.x; i < NBIN; i += 1024) lh[i] = 0u;
    {
        unsigned long long* mz = masks + (size_t)blockIdx.x * 2048;
        mz[threadIdx.x] = 0ULL;
        mz[threadIdx.x + 1024] = 0ULL;
    }
    if (blockIdx.x == 0 && threadIdx.x < 8) cnts[threadIdx.x] = 0u;
    __syncthreads();
    const float4* o4 = (const float4*)(obj + (size_t)img * HW);
    int base = seg * 2048;
#pragma unroll
    for (int k = 0; k < 2; ++k) {
        float4 v = o4[base + threadIdx.x + k * 1024];
        atomicAdd(&lh[fkey(v.x) >> 20], 1u);
        atomicAdd(&lh[fkey(v.y) >> 20], 1u);
        atomicAdd(&lh[fkey(v.z) >> 20], 1u);
        atomicAdd(&lh[fkey(v.w) >> 20], 1u);
    }
    __syncthreads();
    unsigned int* ph = phist + (size_t)blockIdx.x * NBIN;
    for (int i = threadIdx.x; i < NBIN; i += 1024) ph[i] = lh[i];
}

// ============================================================================
// K2: find threshold bin — sum 8 partials per image, then serial scan.
// ============================================================================
__global__ void k_findbin(const unsigned int* __restrict__ phist, unsigned int* selB) {
    __shared__ unsigned int lh[NBIN];
    __shared__ unsigned int chunk[256];
    int img = blockIdx.x;
    int t = threadIdx.x;
    for (int c = 0; c < 16; ++c) {
        int b = c * 256 + t;
        unsigned int v = 0;
#pragma unroll
        for (int q = 0; q < 8; ++q) v += phist[(size_t)(img * 8 + q) * NBIN + b];
        lh[b] = v;
    }
    __syncthreads();
    unsigned int s = 0;
    for (int k = 0; k < 16; ++k) s += lh[t * 16 + k];
    chunk[t] = s;
    __syncthreads();
    if (t == 0) {
        unsigned int run = 0;
        int c;
        for (c = 255; c >= 0; --c) {
            if (run + chunk[c] >= PRE) break;
            run += chunk[c];
        }
        unsigned int B = 0;
        for (int b = c * 16 + 15; b >= c * 16; --b) {
            if (run + lh[b] >= PRE) { B = (unsigned int)b; break; }
            run += lh[b];
        }
        selB[img] = B;
    }
}

// ============================================================================
// K3: compact candidates — block-LDS aggregation, ONE global atomic per
// block per image.
// ============================================================================
__global__ __launch_bounds__(256) void k_compact(const float* __restrict__ obj,
                                                 const unsigned int* __restrict__ selB,
                                                 unsigned int* cnts, unsigned long long* cbuf) {
    __shared__ unsigned long long lbuf[1024];
    __shared__ unsigned int lcnt, lbase;
    int t = blockIdx.x * 256 + threadIdx.x;
    const float4* o4 = (const float4*)obj;
#pragma unroll
    for (int k = 0; k < 2; ++k) {
        if (threadIdx.x == 0) lcnt = 0;
        __syncthreads();
        int p = t + k * 16384;
        int img = p >> 14;
        unsigned int B = selB[img];
        float4 v = o4[p];
        float vs[4] = {v.x, v.y, v.z, v.w};
#pragma unroll
        for (int c = 0; c < 4; ++c) {
            unsigned int key = fkey(vs[c]);
            if ((key >> 20) >= B) {
                unsigned int i = (unsigned int)((p & 16383) * 4 + c);
                unsigned int pos = atomicAdd(&lcnt, 1u);
                lbuf[pos] = ((unsigned long long)key << 32) |
                            (unsigned long long)(0xFFFFFFFFu - i);
            }
        }
        __syncthreads();
        if (threadIdx.x == 0) lbase = atomicAdd(&cnts[img], lcnt);
        __syncthreads();
        unsigned int n = lcnt, base = lbase;
        for (unsigned int q = threadIdx.x; q < n; q += 256) {
            unsigned int gp = base + q;
            if (gp < SORTN) cbuf[img * SORTN + gp] = lbuf[q];
        }
        __syncthreads();
    }
}

// ============================================================================
// K4 (fused rank+decode)
// ============================================================================
__device__ __forceinline__ void decode_one(unsigned long long cv, int img,
                                           const float* __restrict__ boxreg,
                                           float* boxes, float* corn, float4* circ,
                                           unsigned int* varr, float* tscr, int r) {
    int g = img * PRE + r;
    unsigned int key = (unsigned int)(cv >> 32);
    unsigned int idx = (0xFFFFFFFFu - (unsigned int)(cv & 0xFFFFFFFFULL)) & 0xFFFFu;
    float sc = unfkey(key);
    int h = (int)(idx >> 8);
    int w = (int)(idx & 255u);
    const float* rg = boxreg + (size_t)img * 5 * HW;
    float t_ = rg[0 * HW + idx] * 1024.0f;
    float rr = rg[1 * HW + idx] * 1024.0f;
    float bb = rg[2 * HW + idx] * 1024.0f;
    float ll = rg[3 * HW + idx] * 1024.0f;
    float ang = (rg[4 * HW + idx] - 0.5f) * 90.0f;
    float wd = ll + rr;
    float ht = t_ + bb;
    float xc = (float)w * 4.0f + 0.5f * (rr - ll);
    float yc = (float)h * 4.0f + 0.5f * (bb - t_);
    xc = fminf(fmaxf(xc, 0.0f), 1023.0f);
    yc = fminf(fmaxf(yc, 0.0f), 1023.0f);
    bool valid = (sc > SCORE_T) && (wd >= MIN_SZ) && (ht >= MIN_SZ);

    float* bx = boxes + (size_t)g * 5;
    bx[0] = xc; bx[1] = yc; bx[2] = wd; bx[3] = ht; bx[4] = ang;
    tscr[g] = sc;
    varr[g] = valid ? 1u : 0u;

    float th = ang * (float)(3.14159265358979323846 / 180.0);
    float c = cosf(th), s = sinf(th);
    const float dxs[4] = {-0.5f, 0.5f, 0.5f, -0.5f};
    const float dys[4] = {-0.5f, -0.5f, 0.5f, 0.5f};
    float* cr = corn + (size_t)g * 8;
#pragma unroll
    for (int k = 0; k < 4; ++k) {
        float dx = dxs[k] * wd, dy = dys[k] * ht;
        cr[2 * k]     = xc + dx * c - dy * s;
        cr[2 * k + 1] = yc + dx * s + dy * c;
    }
    circ[g] = make_float4(xc, yc, 0.5f * sqrtf(wd * wd + ht * ht) + 0.01f, wd * ht);
}

__global__ __launch_bounds__(256) void k_rankdec(const unsigned int* __restrict__ cnts,
                                                 const unsigned long long* __restrict__ cbuf,
                                                 const float* __restrict__ boxreg,
                                                 float* boxes, float* corn, float4* circ,
                                                 unsigned int* varr, float* tscr) {
    __shared__ unsigned long long keys[SORTN];
    int img = blockIdx.x >> 4;
    int slice = blockIdx.x & 15;
    unsigned int M = cnts[img]; if (M > SORTN) M = SORTN;
    for (unsigned int i = threadIdx.x; i < M; i += 256) keys[i] = cbuf[img * SORTN + i];
    __syncthreads();
    unsigned int cid = (unsigned int)slice * 256 + threadIdx.x;
    if (cid >= M) return;
    unsigned long long cv = keys[cid];
    unsigned int r = 0;
    for (unsigned int j = 0; j < M; ++j) r += (keys[j] > cv) ? 1u : 0u;
    if (r < PRE) decode_one(cv, img, boxreg, boxes, corn, circ, varr, tscr, (int)r);
}

// ============================================================================
// K5 (fused pairs+clip), TRIANGULAR enumeration: 8 iterations cover exactly
// the j>i pairs (no wasted half), fewer drain barriers.
// ============================================================================
__global__ __launch_bounds__(256) void k_pairclip(const float4* __restrict__ circ,
                                                  const float* __restrict__ corn,
                                                  unsigned long long* masks) {
    __shared__ struct {
        float SPX[8][256], SPY[8][256], SQX[8][256], SQY[8][256];
        unsigned int plist[1280];
    } e;
    __shared__ unsigned int pcnt;
    int tid = threadIdx.x;
    if (tid == 0) pcnt = 0;
    __syncthreads();
    int t0 = blockIdx.x * 256 + tid;                      // 131072 threads
    for (int k = 0; k < 8; ++k) {
        int s = t0 + k * 131072;                          // 1048576 slots, 1047552 real
        if (s < TRITOTAL) {
            int img = (s >= TRIPAIRS) ? 1 : 0;
            int p = s - img * TRIPAIRS;
            // triangular: p = r(r+1)/2 + i, pair = (i, r+1), i <= r
            int r = (int)((sqrtf((float)(8 * p + 1)) - 1.0f) * 0.5f);
            while ((r * (r + 1)) / 2 > p) --r;
            while (((r + 1) * (r + 2)) / 2 <= p) ++r;
            int i = p - (r * (r + 1)) / 2;
            int j = r + 1;
            float4 a = circ[img * PRE + i];
            float4 b = circ[img * PRE + j];
            float dx = b.x - a.x, dy = b.y - a.y, rr = a.z + b.z;
            if (dx * dx + dy * dy <= rr * rr)
                e.plist[atomicAdd(&pcnt, 1u)] =
                    ((unsigned int)img << 20) | ((unsigned int)i << 10) | (unsigned int)j;
        }
        __syncthreads();
        unsigned int n = pcnt;                            // uniform
        if (n >= 1024 || k == 7) {
            for (unsigned int q = tid; q < n; q += 256) {
                unsigned int pr = e.plist[q];
                int im = (int)(pr >> 20);
                int bi = (int)((pr >> 10) & 1023);
                int bj = (int)(pr & 1023);
                int ra = im * PRE + bi, rb = im * PRE + bj;
                const float4* ca = (const float4*)(corn + (size_t)ra * 8);
                float4 a0 = ca[0], a1 = ca[1];
                const float4* cb = (const float4*)(corn + (size_t)rb * 8);
                float4 b0 = cb[0], b1 = cb[1];
                float cbx[4] = {b0.x, b0.z, b1.x, b1.z};
                float cby[4] = {b0.y, b0.w, b1.y, b1.w};
                e.SPX[0][tid] = a0.x; e.SPY[0][tid] = a0.y;
                e.SPX[1][tid] = a0.z; e.SPY[1][tid] = a0.w;
                e.SPX[2][tid] = a1.x; e.SPY[2][tid] = a1.y;
                e.SPX[3][tid] = a1.z; e.SPY[3][tid] = a1.w;
                int n2 = 4;
#pragma unroll
                for (int ed = 0; ed < 4; ++ed) {
                    float (*PX)[256] = (ed & 1) ? e.SQX : e.SPX;
                    float (*PY)[256] = (ed & 1) ? e.SQY : e.SPY;
                    float (*QX)[256] = (ed & 1) ? e.SPX : e.SQX;
                    float (*QY)[256] = (ed & 1) ? e.SPY : e.SQY;
                    float p1x = cbx[ed], p1y = cby[ed];
                    int e2 = (ed + 1) & 3;
                    float ex = cbx[e2] - p1x, ey = cby[e2] - p1y;
                    int m = 0;
                    for (int kk = 0; kk < n2; ++kk) {
                        int kn = (kk + 1 < n2) ? kk + 1 : 0;
                        float cx_ = PX[kk][tid], cy_ = PY[kk][tid];
                        float nx_ = PX[kn][tid], ny_ = PY[kn][tid];
                        float dc = ex * (cy_ - p1y) - ey * (cx_ - p1x);
                        float dn = ex * (ny_ - p1y) - ey * (nx_ - p1x);
                        bool ic = dc >= 0.0f;
                        bool inx = dn >= 0.0f;
                        if (ic && m < 8) { QX[m][tid] = cx_; QY[m][tid] = cy_; ++m; }
                        if ((ic != inx) && m < 8) {
                            float den = dc - dn;
                            float safe = (fabsf(den) > 1e-9f) ? den : 1.0f;
                            float tt = dc / safe;
                            QX[m][tid] = cx_ + tt * (nx_ - cx_);
                            QY[m][tid] = cy_ + tt * (ny_ - cy_);
                            ++m;
                        }
                    }
                    n2 = m;
                }
                float inter = 0.0f;
                if (n2 >= 3) {
                    float sa = 0.0f;
                    for (int kk = 0; kk < n2; ++kk) {
                        int kn = (kk + 1 < n2) ? kk + 1 : 0;
                        sa += e.SPX[kk][tid] * e.SPY[kn][tid] - e.SPX[kn][tid] * e.SPY[kk][tid];
                    }
                    inter = 0.5f * fabsf(sa);
                }
                float uni = circ[ra].w + circ[rb].w - inter;
                float iou = inter / fmaxf(uni, 1e-9f);
                if (iou > NMS_THR)
                    atomicOr(&masks[(size_t)ra * 16 + (bj >> 6)], 1ULL << (bj & 63));
            }
            __syncthreads();
            if (tid == 0) pcnt = 0;
            __syncthreads();
        }
    }
}

// ============================================================================
// K6: greedy NMS + output. LDS-staged masks; skip-scan with BATCH-8
// speculative reads (one LDS latency per up to 8 candidate rows).
// ============================================================================
__global__ __launch_bounds__(1024) void k_nms_out(const unsigned long long* __restrict__ masks,
                                                  const unsigned int* __restrict__ varr,
                                                  const float* __restrict__ boxes,
                                                  const float* __restrict__ tscr,
                                                  float* __restrict__ out) {
    __shared__ unsigned long long lm[PRE * 16];   // 128 KB
    __shared__ unsigned long long vmw_s[16];
    __shared__ unsigned short keptIdx[POST];
    __shared__ int sTotal;
    int img = blockIdx.x;
    int t = threadIdx.x;
    const unsigned long long* mbase = masks + (size_t)img * PRE * 16;
    {
        const ulonglong2* src = (const ulonglong2*)mbase;
        ulonglong2* dst = (ulonglong2*)lm;
#pragma unroll
        for (int k = 0; k < 8; ++k) dst[t + k * 1024] = src[t + k * 1024];
    }
    {
        unsigned long long bal = __ballot(varr[img * PRE + t] != 0u);
        if ((t & 63) == 0) vmw_s[t >> 6] = bal;
    }
    __syncthreads();
    if (t < 64) {
        int lane = t;
        int lw = lane & 15;
        unsigned long long vmw = vmw_s[lw];
        unsigned long long supw = 0ULL;
        int cnt = 0;
        for (int b = 0; b < 16 && cnt < POST; ++b) {
            unsigned long long avail = readlane64(vmw, b) & ~readlane64(supw, b);
            while (avail && cnt < POST) {
                unsigned long long a = avail;
                int d0 = __ffsll((long long)a) - 1; a &= a - 1;
                int d1 = a ? __ffsll((long long)a) - 1 : 64; a &= a - 1;
                int d2 = a ? __ffsll((long long)a) - 1 : 64; a &= a - 1;
                int d3 = a ? __ffsll((long long)a) - 1 : 64; a &= a - 1;
                int d4 = a ? __ffsll((long long)a) - 1 : 64; a &= a - 1;
                int d5 = a ? __ffsll((long long)a) - 1 : 64; a &= a - 1;
                int d6 = a ? __ffsll((long long)a) - 1 : 64; a &= a - 1;
                int d7 = a ? __ffsll((long long)a) - 1 : 64; a &= a - 1;
                int r0 = b * 64 + d0;
                int r1 = b * 64 + (d1 & 63);
                int r2 = b * 64 + (d2 & 63);
                int r3 = b * 64 + (d3 & 63);
                int r4 = b * 64 + (d4 & 63);
                int r5 = b * 64 + (d5 & 63);
                int r6 = b * 64 + (d6 & 63);
                int r7 = b * 64 + (d7 & 63);
                unsigned long long w0 = lm[r0 * 16 + lw];
                unsigned long long w1 = lm[r1 * 16 + lw];
                unsigned long long w2 = lm[r2 * 16 + lw];
                unsigned long long w3 = lm[r3 * 16 + lw];
                unsigned long long w4 = lm[r4 * 16 + lw];
                unsigned long long w5 = lm[r5 * 16 + lw];
                unsigned long long w6 = lm[r6 * 16 + lw];
                unsigned long long w7 = lm[r7 * 16 + lw];
                unsigned long long sb = readlane64(w0, b);   // r0 always kept
                supw |= w0;
                if (lane == 0) keptIdx[cnt] = (unsigned short)r0;
                ++cnt;
                if (d1 < 64 && cnt < POST && !((sb >> d1) & 1ULL)) {
                    sb |= readlane64(w1, b); supw |= w1;
                    if (lane == 0) keptIdx[cnt] = (unsigned short)r1;
                    ++cnt;
                }
                if (d2 < 64 && cnt < POST && !((sb >> d2) & 1ULL)) {
                    sb |= readlane64(w2, b); supw |= w2;
                    if (lane == 0) keptIdx[cnt] = (unsigned short)r2;
                    ++cnt;
                }
                if (d3 < 64 && cnt < POST && !((sb >> d3) & 1ULL)) {
                    sb |= readlane64(w3, b); supw |= w3;
                    if (lane == 0) keptIdx[cnt] = (unsigned short)r3;
                    ++cnt;
                }
                if (d4 < 64 && cnt < POST && !((sb >> d4) & 1ULL)) {
                    sb |= readlane64(w4, b); supw |= w4;
                    if (lane == 0) keptIdx[cnt] = (unsigned short)r4;
                    ++cnt;
                }
                if (d5 < 64 && cnt < POST && !((sb >> d5) & 1ULL)) {
                    sb |= readlane64(w5, b); supw |= w5;
                    if (lane == 0) keptIdx[cnt] = (unsigned short)r5;
                    ++cnt;
                }
                if (d6 < 64 && cnt < POST && !((sb >> d6) & 1ULL)) {
                    sb |= readlane64(w6, b); supw |= w6;
                    if (lane == 0) keptIdx[cnt] = (unsigned short)r6;
                    ++cnt;
                }
                if (d7 < 64 && cnt < POST && !((sb >> d7) & 1ULL)) {
                    sb |= readlane64(w7, b); supw |= w7;
                    if (lane == 0) keptIdx[cnt] = (unsigned short)r7;
                    ++cnt;
                }
                avail = a & ~sb;
            }
        }
        if (lane == 0) sTotal = cnt;
    }
    __syncthreads();
    int total = sTotal;
    if (t < POST) {
        float v0 = 0.f, v1 = 0.f, v2 = 0.f, v3 = 0.f, v4 = 0.f, v5 = 0.f;
        if (t < total) {
            int i = keptIdx[t];
            const float* b = boxes + (size_t)(img * PRE + i) * 5;
            v0 = b[0]; v1 = b[1]; v2 = b[2]; v3 = b[3]; v4 = b[4];
            v5 = tscr[img * PRE + i];
        }
        float* o2 = out + (size_t)(img * POST + t) * 6;
        o2[0] = v0; o2[1] = v1; o2[2] = v2; o2[3] = v3; o2[4] = v4; o2[5] = v5;
    }
}

// ---------- workspace layout ----------
enum : size_t {
    OFF_BOX   = 0,         // 40960
    OFF_CORN  = 40960,     // 65536  -> 106496
    OFF_CIRC  = 106496,    // 32768  -> 139264
    OFF_VARR  = 139264,    // 8192   -> 147456
    OFF_TSCR  = 147456,    // 8192   -> 155648
    OFF_MASK  = 155648,    // 262144 -> 417792
    OFF_PHIST = 417792,    // 262144 -> 679936
    OFF_CNTS  = 679936,    // 32     -> 679968
    OFF_SELB  = 679968,    // 16     -> 679984
    OFF_CBUF  = 679984,    // 65536  -> 745520
};

extern "C" void kernel_launch(void* const* d_in, const int* in_sizes, int n_in,
                              void* d_out, int out_size, void* d_ws, size_t ws_size,
                              hipStream_t stream) {
    const float* obj = (const float*)d_in[0];
    const float* boxreg = (const float*)d_in[1];
    float* out = (float*)d_out;

    char* w = (char*)d_ws;
    float* boxes = (float*)(w + OFF_BOX);
    float* corn = (float*)(w + OFF_CORN);
    float4* circ = (float4*)(w + OFF_CIRC);
    unsigned int* varr = (unsigned int*)(w + OFF_VARR);
    float* tscr = (float*)(w + OFF_TSCR);
    unsigned long long* masks = (unsigned long long*)(w + OFF_MASK);
    unsigned int* phist = (unsigned int*)(w + OFF_PHIST);
    unsigned int* cnts = (unsigned int*)(w + OFF_CNTS);
    unsigned int* selB = (unsigned int*)(w + OFF_SELB);
    unsigned long long* cbuf = (unsigned long long*)(w + OFF_CBUF);

    k_front<<<16, 1024, 0, stream>>>(obj, phist, masks, cnts);
    k_findbin<<<N_IMG, 256, 0, stream>>>(phist, selB);
    k_compact<<<64, 256, 0, stream>>>(obj, selB, cnts, cbuf);
    k_rankdec<<<32, 256, 0, stream>>>(cnts, cbuf, boxreg, boxes, corn, circ, varr, tscr);
    k_pairclip<<<512, 256, 0, stream>>>(circ, corn, masks);
    k_nms_out<<<N_IMG, 1024, 0, stream>>>(masks, varr, boxes, tscr, out);
}